// Round 12
// baseline (480.986 us; speedup 1.0000x reference)
//
#include <hip/hip_runtime.h>

// EdgeConv: B=32, N=2048, D=16, PCD=2, K_NN=16, FILTERS=64
// out[b,n,0:64]  = max(y_n, max_k y_{nn_k} - y_n) + b   where y = x@W (linearity)
// out[b,n,64:80] = x[b,n,:]
//
// R12 = R11's windowed-pruning STRUCTURE carried on R10's verified NUMERICS:
//  - staging recipe r10-verbatim: SEPARATE scalar LDS arrays xsL/ysL/sqL,
//    scalar global loads, sq computed in the staging loop. (Empirical law
//    r3..r11: packing sq with coords in one LDS vector => fail 0.453125;
//    separate arrays => pass. Mechanism unknown; recipe is load-bearing.)
//  - distance bit-sequence (verified): sq=fl(fl(x*x)+fl(y*y));
//    dot=fma(qy,ym, fl(qx*xm)); d=fl(fl(sqn+sqm)-fl(2*dot))
//  - pass 1: r10's PAIR-merge sorted-16 network (values-only, order-
//    independent), walking each split's window outward in pairs; break when
//    dx^2 > key15+1e-3 (monotone |dx| -> skipped points provably d>T).
//  - merge (wave0) r10-verbatim -> exact global T.
//  - pass 2: windowed rescan, d<T via atomic slots (set-invariant); ties d==T
//    per-split sorted by orig idx, 4-way merged smallest-first == top_k
//    lower-index-wins.

#define B_  32
#define N_  2048
#define D_  16
#define F_  64
#define K_  16
#define OUTD (F_ + D_)   // 80
#define NQ  64           // queries per block
#define NS  4            // splits: s0 right-even(incl self), s1 right-odd,
                         //         s2 left-odd, s3 left-even
#define MARGIN 1e-3f

// ---------------- K0: per-batch sort by x (bitonic in LDS) ------------------
__global__ __launch_bounds__(256) void sort_kernel(const float* __restrict__ x,
                                                   float* __restrict__ xs,
                                                   float* __restrict__ ys,
                                                   unsigned short* __restrict__ oidx) {
    __shared__ float keyL[N_];    // 8 KB
    __shared__ int   valL[N_];    // 8 KB
    const int bidx = blockIdx.x;
    const int t = threadIdx.x;
    const float* xb = x + (size_t)bidx * N_ * D_;
    for (int m = t; m < N_; m += 256) { keyL[m] = xb[(size_t)m * D_]; valL[m] = m; }
    for (int k = 2; k <= N_; k <<= 1) {
        for (int j = k >> 1; j > 0; j >>= 1) {
            __syncthreads();
            for (int i = t; i < N_; i += 256) {
                int ixj = i ^ j;
                if (ixj > i) {
                    float a = keyL[i], c = keyL[ixj];
                    bool up = ((i & k) == 0);
                    bool sw = up ? (a > c) : (a < c);
                    if (sw) {
                        keyL[i] = c; keyL[ixj] = a;
                        int tv = valL[i]; valL[i] = valL[ixj]; valL[ixj] = tv;
                    }
                }
            }
        }
    }
    __syncthreads();
    float* xso = xs + (size_t)bidx * N_;
    float* yso = ys + (size_t)bidx * N_;
    unsigned short* oio = oidx + (size_t)bidx * N_;
    for (int p = t; p < N_; p += 256) {
        int v = valL[p];
        xso[p] = keyL[p];                         // same bits as xb[v*D_]
        yso[p] = xb[(size_t)v * D_ + 1];
        oio[p] = (unsigned short)v;
    }
}

// ---------------- K1: Y = X * W  (bias folded into fused kernel) ------------
__global__ __launch_bounds__(256) void proj_kernel(const float* __restrict__ x,
                                                   const float* __restrict__ W,
                                                   float* __restrict__ Y) {
    __shared__ float Ws[D_ * F_];     // 4 KB
    __shared__ float xsh[16][D_];     // 1 KB
    const int t = threadIdx.x;
    for (int i = t; i < D_ * F_; i += 256) Ws[i] = W[i];
    const int p0 = blockIdx.x * 16;
    ((float*)xsh)[t] = x[(size_t)p0 * D_ + t];   // coalesced 1 KB
    __syncthreads();
    const int w = t >> 6, f = t & 63;
#pragma unroll
    for (int i = 0; i < 4; i++) {
        const int pw = w * 4 + i;
        float acc = 0.f;
#pragma unroll
        for (int d = 0; d < D_; d++) acc = fmaf(xsh[pw][d], Ws[d * F_ + f], acc);
        Y[(size_t)(p0 + pw) * F_ + f] = acc;
    }
}

// ---------------- K2: exact 16-NN (windowed) + fused pool epilogue ----------
__global__ __launch_bounds__(256, 3) void knn_kernel(const float* __restrict__ x,
                                                     const float* __restrict__ bias,
                                                     const float* __restrict__ Y,
                                                     const float* __restrict__ xs,
                                                     const float* __restrict__ ys,
                                                     const unsigned short* __restrict__ oidx,
                                                     float* __restrict__ out) {
    __shared__ float  xsL[N_];                    // 8 KB  (separate arrays:
    __shared__ float  ysL[N_];                    // 8 KB   the verified
    __shared__ float  sqL[N_];                    // 8 KB   r10 staging recipe)
    __shared__ unsigned short oiL[N_];            // 4 KB
    // overlay: arr lives [barrier2, barrier3); tiebuf/idxL live after barrier3
    __shared__ float  arr_raw[NS - 1][NQ * 17];   // 13056 B
    __shared__ float  Tq[NQ];
    __shared__ int    cnt[NQ];
    __shared__ int    tiecnt[NS][NQ];             // 1 KB
    unsigned short (*tiebuf)[NQ][K_] =
        (unsigned short (*)[NQ][K_])&arr_raw[0][0];               // 8 KB
    int (*idxL)[K_] = (int (*)[K_])((char*)&arr_raw[0][0] + 8192); // 4 KB

    const int b = blockIdx.x >> 5;                // 32 blocks per batch
    const int qbase = (blockIdx.x & 31) * NQ;
    const int t = threadIdx.x;
    const int s = t >> 6;                         // wave id = split id
    const int qi = t & 63;
    const int q = qbase + qi;                     // SORTED position of query

    const float* xsb = xs + (size_t)b * N_;
    const float* ysb = ys + (size_t)b * N_;
    const unsigned short* oib = oidx + (size_t)b * N_;
    for (int m = t; m < N_; m += 256) {
        float xv = xsb[m];
        float yv = ysb[m];
        xsL[m] = xv;
        ysL[m] = yv;
        sqL[m] = __fadd_rn(__fmul_rn(xv, xv), __fmul_rn(yv, yv));
        oiL[m] = oib[m];
    }
    if (t < NQ) cnt[t] = 0;
    __syncthreads();                              // barrier 1

    const float qx = xsL[q];
    const float qy = ysL[q];
    const float sqn = sqL[q];

    const int pstart = q + ((s == 0) ? 0 : (s == 1) ? 1 : (s == 2) ? -1 : -2);
    const int pstep  = (s < 2) ? 2 : -2;

    // ---- pass 1: r10 pair-merge sorted-16 network over this split's window
    float key[K_];
#pragma unroll
    for (int j = 0; j < K_; j++) key[j] = INFINITY;

    for (int p = pstart; (unsigned)p < (unsigned)N_; p += 2 * pstep) {
        float xma = xsL[p];
        float dxa = xma - qx;
        if (dxa * dxa > key[K_ - 1] + MARGIN) break;  // monotone |dx| -> safe
        float dota = __fmaf_rn(qy, ysL[p], __fmul_rn(qx, xma));
        float da   = __fsub_rn(__fadd_rn(sqn, sqL[p]), __fmul_rn(2.f, dota));
        float db = INFINITY;                          // INF pad: inert in network
        const int p2 = p + pstep;
        if ((unsigned)p2 < (unsigned)N_) {
            float xmb = xsL[p2];
            float dotb = __fmaf_rn(qy, ysL[p2], __fmul_rn(qx, xmb));
            db = __fsub_rn(__fadd_rn(sqn, sqL[p2]), __fmul_rn(2.f, dotb));
        }
        float y0 = fminf(da, db), y1 = fmaxf(da, db);
#pragma unroll
        for (int j = K_ - 1; j >= 2; j--)
            key[j] = fminf(fminf(key[j], fmaxf(key[j - 1], y0)),
                           fmaxf(key[j - 2], y1));
        key[1] = fminf(fminf(key[1], fmaxf(key[0], y0)), y1);
        key[0] = fminf(key[0], y0);
    }

    if (s > 0) {
#pragma unroll
        for (int j = 0; j < K_; j++) arr_raw[s - 1][qi * 17 + j] = key[j];
    }
    __syncthreads();                              // barrier 2

    // ---- merge (wave 0): stream splits 1..3 sorted-16s (r10-verbatim)
    if (s == 0) {
        for (int ss = 0; ss < NS - 1; ss++) {
#pragma unroll
            for (int j = 0; j < K_; j += 2) {
                float y0 = arr_raw[ss][qi * 17 + j];
                float y1 = arr_raw[ss][qi * 17 + j + 1];   // y0 <= y1
#pragma unroll
                for (int jj = K_ - 1; jj >= 2; jj--)
                    key[jj] = fminf(fminf(key[jj], fmaxf(key[jj - 1], y0)),
                                    fmaxf(key[jj - 2], y1));
                key[1] = fminf(fminf(key[1], fmaxf(key[0], y0)), y1);
                key[0] = fminf(key[0], y0);
            }
        }
        Tq[qi] = key[K_ - 1];     // exact global 16th-smallest distance
    }
    __syncthreads();                              // barrier 3 (arr dead now)

    // ---- pass 2: windowed rescan with exact T bound
    const float T = Tq[qi];
    int tc = 0;
    for (int p = pstart; (unsigned)p < (unsigned)N_; p += pstep) {
        float xm = xsL[p];
        float dx = xm - qx;
        if (dx * dx > T + MARGIN) break;          // beyond: d > T provably
        float dot = __fmaf_rn(qy, ysL[p], __fmul_rn(qx, xm));
        float d   = __fsub_rn(__fadd_rn(sqn, sqL[p]), __fmul_rn(2.f, dot));
        if (d < T) {
            int slot = atomicAdd(&cnt[qi], 1);    // #{d<T} <= 15, slots unique
            idxL[qi][slot] = (int)oiL[p];
        } else if (d == T) {
            // sorted insert (ascending ORIG idx), keep 16 smallest
            int oi = (int)oiL[p];
            int pos = (tc < K_) ? tc : K_;
            while (pos > 0 && (int)tiebuf[s][qi][pos - 1] > oi) {
                if (pos < K_) tiebuf[s][qi][pos] = tiebuf[s][qi][pos - 1];
                pos--;
            }
            if (pos < K_) tiebuf[s][qi][pos] = (unsigned short)oi;
            tc++;
        }
    }
    tiecnt[s][qi] = (tc < K_) ? tc : K_;
    __syncthreads();                              // barrier 4

    // ---- tie fill (wave 0): globally smallest orig-idx ties first
    if (s == 0) {
        int c1 = cnt[qi];
        int l0 = tiecnt[0][qi], l1 = tiecnt[1][qi];
        int l2 = tiecnt[2][qi], l3 = tiecnt[3][qi];
        int p0 = 0, p1 = 0, p2 = 0, p3 = 0;
        for (int w = c1; w < K_; w++) {           // need >= 1 always
            int v0 = (p0 < l0) ? (int)tiebuf[0][qi][p0] : 0x7fffffff;
            int v1 = (p1 < l1) ? (int)tiebuf[1][qi][p1] : 0x7fffffff;
            int v2 = (p2 < l2) ? (int)tiebuf[2][qi][p2] : 0x7fffffff;
            int v3 = (p3 < l3) ? (int)tiebuf[3][qi][p3] : 0x7fffffff;
            int m01 = (v0 <= v1) ? v0 : v1;
            int m23 = (v2 <= v3) ? v2 : v3;
            int mv  = (m01 <= m23) ? m01 : m23;
            idxL[qi][w] = mv;
            if (mv == v0) p0++;
            else if (mv == v1) p1++;
            else if (mv == v2) p2++;
            else p3++;
        }
    }
    __syncthreads();                              // barrier 5

    // ---- fused pool epilogue: wave s handles local queries s*16..s*16+15
    const int f = qi;                             // lane = filter
    const float bf = bias[f];
    const float* Yb = Y + (size_t)b * N_ * F_;
    const float* xb = x + (size_t)b * N_ * D_;
    for (int i = 0; i < 16; i++) {
        const int qq = s * 16 + i;                // local query id
        const int oq = (int)oiL[qbase + qq];      // orig point id
        const float yn = Yb[(size_t)oq * F_ + f];
        float M = -INFINITY;
#pragma unroll
        for (int k = 0; k < K_; k++) {
            int m = idxL[qq][k];                  // wave-uniform -> broadcast
            M = fmaxf(M, Yb[(size_t)m * F_ + f]); // coalesced 256B row
        }
        const size_t pb = (size_t)b * N_ + oq;
        out[pb * OUTD + f] = fmaxf(yn, M - yn) + bf;
        if (f < D_) out[pb * OUTD + F_ + f] = xb[(size_t)oq * D_ + f];
    }
}

extern "C" void kernel_launch(void* const* d_in, const int* in_sizes, int n_in,
                              void* d_out, int out_size, void* d_ws, size_t ws_size,
                              hipStream_t stream) {
    const float* x    = (const float*)d_in[0];
    const float* W    = (const float*)d_in[1];
    const float* bias = (const float*)d_in[2];
    float* out = (float*)d_out;

    char* ws = (char*)d_ws;
    float* Y             = (float*)ws;                                  // 16,777,216 B
    float* xs            = (float*)(ws + 16777216);                     //    262,144 B
    float* ys            = (float*)(ws + 16777216 + 262144);            //    262,144 B
    unsigned short* oidx = (unsigned short*)(ws + 16777216 + 2*262144); //    131,072 B

    sort_kernel<<<B_, 256, 0, stream>>>(x, xs, ys, oidx);
    proj_kernel<<<B_ * N_ / 16, 256, 0, stream>>>(x, W, Y);
    knn_kernel <<<B_ * (N_ / NQ), 256, 0, stream>>>(x, bias, Y, xs, ys, oidx, out);
}

// Round 14
// 442.277 us; speedup vs baseline: 1.0875x; 1.0875x over previous
//
#include <hip/hip_runtime.h>

// EdgeConv: B=32, N=2048, D=16, PCD=2, K_NN=16, FILTERS=64
// out[b,n,0:64]  = max(y_n, max_k y_{nn_k} - y_n) + b   where y = x@W (linearity)
// out[b,n,64:80] = x[b,n,:]
//
// R14 = R13 with ONE fix: binary search starts at st=2048 (12 steps) so
// lo/hi can reach 2048. R13's 11-step version capped hi at 2047, excluding
// sorted index 2047 from pass-2; for q>=1984 that point is in U (central),
// can be a true neighbor -> tie-fill starved -> 0x7fffffff sentinel ->
// wild Y read -> the observed memory-fault crash.
// Structure (r13): A-1 fixed 128 central cands -> T0; masked binsearch
// window [lo,hi) from T0; A-2 extension pair-merge -> exact T; pass-2
// atomic-slot d<T + orig-idx-sorted tie merge; fused pool epilogue.
// Numerics carrier (LOAD-BEARING, from passing rounds): separate scalar LDS
// arrays xsL/ysL/sqL, sq in staging loop; dist bit-seq
//   sq=fl(fl(x*x)+fl(y*y)); dot=fma(qy,ym,fl(qx*xm)); d=fl(fl(sqn+sqm)-fl(2dot))

#define B_  32
#define N_  2048
#define D_  16
#define F_  64
#define K_  16
#define OUTD (F_ + D_)   // 80
#define NQ  64           // queries per block
#define NS  4            // splits (= waves per block)
#define MARGIN 1e-3f

// ---------------- K0: per-batch sort by x (bitonic in LDS, r12-verbatim) ----
__global__ __launch_bounds__(256) void sort_kernel(const float* __restrict__ x,
                                                   float* __restrict__ xs,
                                                   float* __restrict__ ys,
                                                   unsigned short* __restrict__ oidx) {
    __shared__ float keyL[N_];    // 8 KB
    __shared__ int   valL[N_];    // 8 KB
    const int bidx = blockIdx.x;
    const int t = threadIdx.x;
    const float* xb = x + (size_t)bidx * N_ * D_;
    for (int m = t; m < N_; m += 256) { keyL[m] = xb[(size_t)m * D_]; valL[m] = m; }
    for (int k = 2; k <= N_; k <<= 1) {
        for (int j = k >> 1; j > 0; j >>= 1) {
            __syncthreads();
            for (int i = t; i < N_; i += 256) {
                int ixj = i ^ j;
                if (ixj > i) {
                    float a = keyL[i], c = keyL[ixj];
                    bool up = ((i & k) == 0);
                    bool sw = up ? (a > c) : (a < c);
                    if (sw) {
                        keyL[i] = c; keyL[ixj] = a;
                        int tv = valL[i]; valL[i] = valL[ixj]; valL[ixj] = tv;
                    }
                }
            }
        }
    }
    __syncthreads();
    float* xso = xs + (size_t)bidx * N_;
    float* yso = ys + (size_t)bidx * N_;
    unsigned short* oio = oidx + (size_t)bidx * N_;
    for (int p = t; p < N_; p += 256) {
        int v = valL[p];
        xso[p] = keyL[p];                         // same bits as xb[v*D_]
        yso[p] = xb[(size_t)v * D_ + 1];
        oio[p] = (unsigned short)v;
    }
}

// ---------------- K1: Y = X * W  (bias folded into fused kernel) ------------
__global__ __launch_bounds__(256) void proj_kernel(const float* __restrict__ x,
                                                   const float* __restrict__ W,
                                                   float* __restrict__ Y) {
    __shared__ float Ws[D_ * F_];     // 4 KB
    __shared__ float xsh[16][D_];     // 1 KB
    const int t = threadIdx.x;
    for (int i = t; i < D_ * F_; i += 256) Ws[i] = W[i];
    const int p0 = blockIdx.x * 16;
    ((float*)xsh)[t] = x[(size_t)p0 * D_ + t];   // coalesced 1 KB
    __syncthreads();
    const int w = t >> 6, f = t & 63;
#pragma unroll
    for (int i = 0; i < 4; i++) {
        const int pw = w * 4 + i;
        float acc = 0.f;
#pragma unroll
        for (int d = 0; d < D_; d++) acc = fmaf(xsh[pw][d], Ws[d * F_ + f], acc);
        Y[(size_t)(p0 + pw) * F_ + f] = acc;
    }
}

// ---------------- K2: exact 16-NN (windowed, branchless) + fused pool -------
__global__ __launch_bounds__(256, 3) void knn_kernel(const float* __restrict__ x,
                                                     const float* __restrict__ bias,
                                                     const float* __restrict__ Y,
                                                     const float* __restrict__ xs,
                                                     const float* __restrict__ ys,
                                                     const unsigned short* __restrict__ oidx,
                                                     float* __restrict__ out) {
    __shared__ float  xsL[N_];                    // 8 KB  (separate arrays:
    __shared__ float  ysL[N_];                    // 8 KB   verified staging
    __shared__ float  sqL[N_];                    // 8 KB   recipe)
    __shared__ unsigned short oiL[N_];            // 4 KB
    // overlay: arr live until barrier5; tiebuf/idxL live after barrier5
    __shared__ float  arr_raw[NS - 1][NQ * 17];   // 13056 B
    __shared__ float  Tq[NQ];
    __shared__ int    cnt[NQ];
    __shared__ int    tiecnt[NS][NQ];             // 1 KB
    unsigned short (*tiebuf)[NQ][K_] =
        (unsigned short (*)[NQ][K_])&arr_raw[0][0];               // 8 KB
    int (*idxL)[K_] = (int (*)[K_])((char*)&arr_raw[0][0] + 8192); // 4 KB

    const int b = blockIdx.x >> 5;                // 32 blocks per batch
    const int qbase = (blockIdx.x & 31) * NQ;
    const int t = threadIdx.x;
    const int s = t >> 6;                         // wave id = split id
    const int qi = t & 63;
    const int q = qbase + qi;                     // SORTED position of query

    const float* xsb = xs + (size_t)b * N_;
    const float* ysb = ys + (size_t)b * N_;
    const unsigned short* oib = oidx + (size_t)b * N_;
    for (int m = t; m < N_; m += 256) {
        float xv = xsb[m];
        float yv = ysb[m];
        xsL[m] = xv;
        ysL[m] = yv;
        sqL[m] = __fadd_rn(__fmul_rn(xv, xv), __fmul_rn(yv, yv));
        oiL[m] = oib[m];
    }
    if (t < NQ) cnt[t] = 0;
    __syncthreads();                              // barrier 1

    const float qx = xsL[q];
    const float qy = ysL[q];
    const float sqn = sqL[q];

#define DISTP(p, dd) { float xm_ = xsL[p]; \
    float dot_ = __fmaf_rn(qy, ysL[p], __fmul_rn(qx, xm_)); \
    dd = __fsub_rn(__fadd_rn(sqn, sqL[p]), __fmul_rn(2.f, dot_)); }

#define PMERGE(Karr, dA, dB) { \
    float y0_ = fminf(dA, dB), y1_ = fmaxf(dA, dB); \
    _Pragma("unroll") \
    for (int j_ = K_ - 1; j_ >= 2; j_--) \
        Karr[j_] = fminf(fminf(Karr[j_], fmaxf(Karr[j_ - 1], y0_)), \
                         fmaxf(Karr[j_ - 2], y1_)); \
    Karr[1] = fminf(fminf(Karr[1], fmaxf(Karr[0], y0_)), y1_); \
    Karr[0] = fminf(Karr[0], y0_); }

    // ---- A-1: fixed 128 central candidates, split 4x32, fully unrolled
    float key[K_];
#pragma unroll
    for (int j = 0; j < K_; j++) key[j] = INFINITY;

    const int base = q - 64 + 32 * s;
#pragma unroll
    for (int i = 0; i < 16; i++) {
        int pa = base + 2 * i, pb = pa + 1;
        float da = INFINITY, db = INFINITY;
        if ((unsigned)pa < (unsigned)N_) DISTP(pa, da)
        if ((unsigned)pb < (unsigned)N_) DISTP(pb, db)
        PMERGE(key, da, db)
    }
    if (s > 0) {
#pragma unroll
        for (int j = 0; j < K_; j++) arr_raw[s - 1][qi * 17 + j] = key[j];
    }
    __syncthreads();                              // barrier 2

    // ---- merge1 (wave 0): -> T0 = exact 16th smallest of the 128 central
    if (s == 0) {
        for (int ss = 0; ss < NS - 1; ss++) {
#pragma unroll
            for (int j = 0; j < K_; j += 2) {
                float y0 = arr_raw[ss][qi * 17 + j];
                float y1 = arr_raw[ss][qi * 17 + j + 1];   // y0 <= y1
                PMERGE(key, y0, y1)
            }
        }
        Tq[qi] = key[K_ - 1];
    }
    __syncthreads();                              // barrier 3

    // ---- window [lo,hi) from T0: 12-step masked binary searches (reach 2048!)
    const float T0 = Tq[qi];
    const float s0 = sqrtf(T0 + 2e-3f);           // s0^2 >= T0+1e-3 w/ rounding
    const float xlo = qx - s0, xhi = qx + s0;
    int lo = 0, hi = 0;
#pragma unroll
    for (int st = 2048; st; st >>= 1) {           // FIX: st from 2048 (12 steps)
        int ia = lo + st - 1; ia = (ia > N_ - 1) ? (N_ - 1) : ia;
        int ib = hi + st - 1; ib = (ib > N_ - 1) ? (N_ - 1) : ib;
        float va = xsL[ia], vb = xsL[ib];
        if (lo + st <= N_ && va < xlo)  lo += st;
        if (hi + st <= N_ && vb <= xhi) hi += st;
    }
    const int Lc = (q - 64 > 0) ? (q - 64) : 0;
    const int Rc = (q + 64 < N_) ? (q + 64) : N_;

    // ---- A-2: extension [lo,Lc) u [Rc,hi), stride-4 split, pair-merge
    float key2[K_];
#pragma unroll
    for (int j = 0; j < K_; j++) key2[j] = INFINITY;

    for (int pa = lo + s; pa < Lc; pa += 8) {
        int pb = pa + 4;
        float da, db = INFINITY;
        DISTP(pa, da)
        if (pb < Lc) DISTP(pb, db)
        PMERGE(key2, da, db)
    }
    for (int pa = Rc + s; pa < hi; pa += 8) {
        int pb = pa + 4;
        float da, db = INFINITY;
        DISTP(pa, da)
        if (pb < hi) DISTP(pb, db)
        PMERGE(key2, da, db)
    }
    if (s > 0) {
#pragma unroll
        for (int j = 0; j < K_; j++) arr_raw[s - 1][qi * 17 + j] = key2[j];
    }
    __syncthreads();                              // barrier 4

    // ---- merge2 (wave 0): key (central) + own key2 + 3 arr key2s -> exact T
    if (s == 0) {
#pragma unroll
        for (int j = 0; j < K_; j += 2) {
            float y0 = key2[j], y1 = key2[j + 1];          // sorted -> y0<=y1
            PMERGE(key, y0, y1)
        }
        for (int ss = 0; ss < NS - 1; ss++) {
#pragma unroll
            for (int j = 0; j < K_; j += 2) {
                float y0 = arr_raw[ss][qi * 17 + j];
                float y1 = arr_raw[ss][qi * 17 + j + 1];
                PMERGE(key, y0, y1)
            }
        }
        Tq[qi] = key[K_ - 1];     // exact global 16th-smallest distance
    }
    __syncthreads();                              // barrier 5 (arr dead now)

    // ---- pass 2: [lo,hi) stride-4, count-based exit (r12 emission verbatim)
    const float T = Tq[qi];
    int tc = 0;
    for (int p = lo + s; p < hi; p += 4) {
        float d; DISTP(p, d)
        if (d < T) {
            int slot = atomicAdd(&cnt[qi], 1);    // #{d<T} <= 15, slots unique
            idxL[qi][slot] = (int)oiL[p];
        } else if (d == T) {
            int oi = (int)oiL[p];
            int pos = (tc < K_) ? tc : K_;
            while (pos > 0 && (int)tiebuf[s][qi][pos - 1] > oi) {
                if (pos < K_) tiebuf[s][qi][pos] = tiebuf[s][qi][pos - 1];
                pos--;
            }
            if (pos < K_) tiebuf[s][qi][pos] = (unsigned short)oi;
            tc++;
        }
    }
    tiecnt[s][qi] = (tc < K_) ? tc : K_;
    __syncthreads();                              // barrier 6

    // ---- tie fill (wave 0): globally smallest orig-idx ties first
    if (s == 0) {
        int c1 = cnt[qi];
        int l0 = tiecnt[0][qi], l1 = tiecnt[1][qi];
        int l2 = tiecnt[2][qi], l3 = tiecnt[3][qi];
        int p0 = 0, p1 = 0, p2 = 0, p3 = 0;
        for (int w = c1; w < K_; w++) {           // need >= 1 always
            int v0 = (p0 < l0) ? (int)tiebuf[0][qi][p0] : 0x7fffffff;
            int v1 = (p1 < l1) ? (int)tiebuf[1][qi][p1] : 0x7fffffff;
            int v2 = (p2 < l2) ? (int)tiebuf[2][qi][p2] : 0x7fffffff;
            int v3 = (p3 < l3) ? (int)tiebuf[3][qi][p3] : 0x7fffffff;
            int m01 = (v0 <= v1) ? v0 : v1;
            int m23 = (v2 <= v3) ? v2 : v3;
            int mv  = (m01 <= m23) ? m01 : m23;
            idxL[qi][w] = mv;
            if (mv == v0) p0++;
            else if (mv == v1) p1++;
            else if (mv == v2) p2++;
            else p3++;
        }
    }
    __syncthreads();                              // barrier 7

    // ---- fused pool epilogue (r12-verbatim)
    const int f = qi;                             // lane = filter
    const float bf = bias[f];
    const float* Yb = Y + (size_t)b * N_ * F_;
    const float* xb = x + (size_t)b * N_ * D_;
    for (int i = 0; i < 16; i++) {
        const int qq = s * 16 + i;                // local query id
        const int oq = (int)oiL[qbase + qq];      // orig point id
        const float yn = Yb[(size_t)oq * F_ + f];
        float M = -INFINITY;
#pragma unroll
        for (int k = 0; k < K_; k++) {
            int m = idxL[qq][k];                  // wave-uniform -> broadcast
            M = fmaxf(M, Yb[(size_t)m * F_ + f]); // coalesced 256B row
        }
        const size_t pb = (size_t)b * N_ + oq;
        out[pb * OUTD + f] = fmaxf(yn, M - yn) + bf;
        if (f < D_) out[pb * OUTD + F_ + f] = xb[(size_t)oq * D_ + f];
    }
}

extern "C" void kernel_launch(void* const* d_in, const int* in_sizes, int n_in,
                              void* d_out, int out_size, void* d_ws, size_t ws_size,
                              hipStream_t stream) {
    const float* x    = (const float*)d_in[0];
    const float* W    = (const float*)d_in[1];
    const float* bias = (const float*)d_in[2];
    float* out = (float*)d_out;

    char* ws = (char*)d_ws;
    float* Y             = (float*)ws;                                  // 16,777,216 B
    float* xs            = (float*)(ws + 16777216);                     //    262,144 B
    float* ys            = (float*)(ws + 16777216 + 262144);            //    262,144 B
    unsigned short* oidx = (unsigned short*)(ws + 16777216 + 2*262144); //    131,072 B

    sort_kernel<<<B_, 256, 0, stream>>>(x, xs, ys, oidx);
    proj_kernel<<<B_ * N_ / 16, 256, 0, stream>>>(x, W, Y);
    knn_kernel <<<B_ * (N_ / NQ), 256, 0, stream>>>(x, bias, Y, xs, ys, oidx, out);
}